// Round 4
// baseline (350.850 us; speedup 1.0000x reference)
//
#include <hip/hip_runtime.h>
#include <stdint.h>

#define BB 8192
#define NN 50

typedef _Float16 half8 __attribute__((ext_vector_type(8)));
typedef _Float16 half4v __attribute__((ext_vector_type(4)));
typedef float floatx4 __attribute__((ext_vector_type(4)));

union FragU { uint4 u; half8 h; };
static __device__ __forceinline__ half8 u2h(uint4 u) { FragU f; f.u = u; return f.h; }
union F2U { uint2 u; half4v h; };
static __device__ __forceinline__ floatx4 up4(uint2 u) {
    F2U f; f.u = u; floatx4 r;
    r[0] = (float)f.h[0]; r[1] = (float)f.h[1]; r[2] = (float)f.h[2]; r[3] = (float)f.h[3];
    return r;
}
static __device__ __forceinline__ uint32_t pk2u(float a, float b) {
    auto p = __builtin_amdgcn_cvt_pkrtz(a, b);
    uint32_t u; __builtin_memcpy(&u, &p, 4); return u;
}
static __device__ __forceinline__ uint2 pkx4(floatx4 v) {
    return make_uint2(pk2u(v[0], v[1]), pk2u(v[2], v[3]));
}
static __device__ __forceinline__ uint4 pkf8(const float* p) {
    float4 a = *(const float4*)p, b = *(const float4*)(p + 4);
    return make_uint4(pk2u(a.x, a.y), pk2u(a.z, a.w), pk2u(b.x, b.y), pk2u(b.z, b.w));
}
#define MFMA(A, B, C) __builtin_amdgcn_mfma_f32_16x16x32_f16((A), (B), (C), 0, 0, 0)
static __device__ __forceinline__ float fsig(float x)   { return 1.0f / (1.0f + __expf(-x)); }
static __device__ __forceinline__ float ftanhf(float x) { return 1.0f - 2.0f / (__expf(2.0f * x) + 1.0f); }

// One wave = 16 items (one side). 256 blocks x 256 thr; blocks 0..127 src, 128..255 dst.
// Fused: gi(t) = G*nf(t) + Bu*tvec(t), G = Wih@Wfeat^T, Bu = Wih@[time|edge|struct|bias]
// (biases folded; b_hh_n kept as C-init of the hh MFMA). W_hh A-frags in 96 VGPRs.
// A-frag: A[m=lane&15][k=8*(lane>>4)+j]; B-frag: B[k][n=lane&15]; D: col=lane&15, row=4*(lane>>4)+reg.
__global__ __launch_bounds__(256, 1)
void dygkt4(const float* __restrict__ nodef, const float* __restrict__ edgef,
            const int* __restrict__ src_ids, const int* __restrict__ dst_ids,
            const float* __restrict__ times,
            const int* __restrict__ s_nids, const int* __restrict__ s_eids,
            const float* __restrict__ s_ts,
            const int* __restrict__ d_nids, const int* __restrict__ d_eids,
            const float* __restrict__ d_ts,
            const float* __restrict__ W_feat, const float* __restrict__ b_feat,
            const float* __restrict__ W_edge, const float* __restrict__ b_edge,
            const float* __restrict__ W_time, const float* __restrict__ b_time,
            const float* __restrict__ W_str,  const float* __restrict__ b_str,
            const float* __restrict__ W_out,  const float* __restrict__ b_out,
            const float* __restrict__ time_w, const float* __restrict__ time_b,
            const float* __restrict__ sWih, const float* __restrict__ sWhh,
            const float* __restrict__ sbih, const float* __restrict__ sbhh,
            const float* __restrict__ dWih, const float* __restrict__ dWhh,
            const float* __restrict__ dbih, const float* __restrict__ dbhh,
            float* __restrict__ out)
{
    __shared__ _Float16 Gsh[192 * 72];   // 27648 B: G (src) / W_feat^T (dst) A-frag layout
    __shared__ _Float16 Bsh[192 * 40];   // 15360 B: Bu A-frag layout (K=32)
    __shared__ uint4    woA[8][64];      //  8192 B: W_out^T A-frags
    __shared__ uint4    wtT[4][64];      //  4096 B: tail bundle A-frags
    __shared__ _Float16 hbuf[4 * 16 * 72]; // 9216 B: per-wave h^T staging
    // total 64512 B

    const int tid = threadIdx.x, wave = tid >> 6, lane = tid & 63;
    const int g = lane >> 4, i16 = lane & 15;
    const bool is_src = blockIdx.x < 128;
    const int ib0 = (int)(blockIdx.x & 127) * 64 + wave * 16;
    const int b = ib0 + i16;
    const floatx4 z4 = {0, 0, 0, 0};

    const float* WI = is_src ? sWih : dWih;
    const float* WH = is_src ? sWhh : dWhh;
    const float* BI = is_src ? sbih : dbih;
    const float* BH = is_src ? sbhh : dbhh;

    // ---- stage W_out^T A-frags ----
    for (int q = tid; q < 512; q += 256) {
        int l = q & 63, tt = q >> 6;
        int kh = tt >> 2, mt = tt & 3, gg = l >> 4, ii = l & 15;
        float w[8];
        #pragma unroll
        for (int j = 0; j < 8; ++j)
            w[j] = W_out[(32 * kh + 8 * gg + j) * 64 + 16 * mt + ii];
        woA[tt][l] = make_uint4(pk2u(w[0],w[1]), pk2u(w[2],w[3]), pk2u(w[4],w[5]), pk2u(w[6],w[7]));
    }
    // ---- stage tail bundle A-frags (k<16 W_time, 16 W_edge, 17 W_str, 18 be+bt, 20 b_feat) ----
    {
        int l = tid & 63, mt = tid >> 6, gg = l >> 4, ii = l & 15;
        float v[8];
        #pragma unroll
        for (int j = 0; j < 8; ++j) {
            int k = 8 * gg + j, dim = 16 * mt + ii;
            float x = 0.0f;
            if (k < 16)       x = W_time[k * 64 + dim];
            else if (k == 16) x = W_edge[dim];
            else if (k == 17) x = W_str[dim];
            else if (k == 18) x = b_edge[dim] + b_time[dim];
            else if (k == 20) x = b_feat[dim];
            v[j] = x;
        }
        wtT[mt][l] = make_uint4(pk2u(v[0],v[1]), pk2u(v[2],v[3]), pk2u(v[4],v[5]), pk2u(v[6],v[7]));
    }
    // ---- zero h staging ----
    for (int q = tid; q < 2304; q += 256) ((uint32_t*)hbuf)[q] = 0;

    // ---- W_hh A-frags -> 96 VGPRs ----
    uint4 whh[12][2];
    #pragma unroll
    for (int mt = 0; mt < 12; ++mt)
        #pragma unroll
        for (int kh = 0; kh < 2; ++kh)
            whh[mt][kh] = pkf8(WH + (size_t)(16 * mt + i16) * 64 + 32 * kh + 8 * g);

    // ---- precompute G (src) / stage W_feat^T (dst) ----
    if (is_src) {
        for (int mt = wave; mt < 12; mt += 4) {
            uint4 A0 = pkf8(WI + (size_t)(16 * mt + i16) * 64 + 8 * g);
            uint4 A1 = pkf8(WI + (size_t)(16 * mt + i16) * 64 + 32 + 8 * g);
            #pragma unroll
            for (int nt = 0; nt < 4; ++nt) {
                uint4 B0 = pkf8(W_feat + (size_t)(16 * nt + i16) * 64 + 8 * g);
                uint4 B1 = pkf8(W_feat + (size_t)(16 * nt + i16) * 64 + 32 + 8 * g);
                floatx4 D = MFMA(u2h(A1), u2h(B1), MFMA(u2h(A0), u2h(B0), z4));
                #pragma unroll
                for (int r = 0; r < 4; ++r)
                    Gsh[(16 * mt + 4 * g + r) * 72 + 16 * nt + i16] = (_Float16)D[r];
            }
            // Bu tiles for this mt
            #pragma unroll
            for (int nt = 0; nt < 2; ++nt) {
                uint4 bB[2];
                #pragma unroll
                for (int kh = 0; kh < 2; ++kh) {
                    float v[8];
                    #pragma unroll
                    for (int jj = 0; jj < 8; ++jj) {
                        int d = 32 * kh + 8 * g + jj;
                        float x = 0.0f;
                        if (nt == 0) x = W_time[i16 * 64 + d];
                        else if (i16 == 0) x = W_edge[d];
                        else if (i16 == 1) x = W_str[d];
                        else if (i16 == 2) x = b_edge[d] + b_time[d] + b_feat[d] + 2.0f * b_str[d];
                        v[jj] = x;
                    }
                    bB[kh] = make_uint4(pk2u(v[0],v[1]), pk2u(v[2],v[3]), pk2u(v[4],v[5]), pk2u(v[6],v[7]));
                }
                floatx4 D = MFMA(u2h(A1), u2h(bB[1]), MFMA(u2h(A0), u2h(bB[0]), z4));
                if (nt == 1 && i16 == 2) {
                    #pragma unroll
                    for (int r = 0; r < 4; ++r)
                        D[r] += BI[16 * mt + 4 * g + r] + (mt < 8 ? BH[16 * mt + 4 * g + r] : 0.0f);
                }
                #pragma unroll
                for (int r = 0; r < 4; ++r)
                    Bsh[(16 * mt + 4 * g + r) * 40 + 16 * nt + i16] = (_Float16)D[r];
            }
        }
    } else {
        for (int p = tid; p < 4096; p += 256) {
            int m = p & 63, j = p >> 6;
            Gsh[m * 72 + j] = (_Float16)W_feat[j * 64 + m];
        }
        for (int mt = wave; mt < 12; mt += 4) {
            uint4 A0 = pkf8(WI + (size_t)(16 * mt + i16) * 64 + 8 * g);
            uint4 A1 = pkf8(WI + (size_t)(16 * mt + i16) * 64 + 32 + 8 * g);
            #pragma unroll
            for (int nt = 0; nt < 2; ++nt) {
                uint4 bB[2];
                #pragma unroll
                for (int kh = 0; kh < 2; ++kh) {
                    float v[8];
                    #pragma unroll
                    for (int jj = 0; jj < 8; ++jj) {
                        int d = 32 * kh + 8 * g + jj;
                        float x = 0.0f;
                        if (nt == 0) x = W_time[i16 * 64 + d];
                        else if (i16 == 0) x = W_edge[d];
                        else if (i16 == 1) x = W_str[d];
                        else if (i16 == 2) x = b_edge[d] + b_time[d] + b_str[d];
                        v[jj] = x;
                    }
                    bB[kh] = make_uint4(pk2u(v[0],v[1]), pk2u(v[2],v[3]), pk2u(v[4],v[5]), pk2u(v[6],v[7]));
                }
                floatx4 D = MFMA(u2h(A1), u2h(bB[1]), MFMA(u2h(A0), u2h(bB[0]), z4));
                if (nt == 1 && i16 == 2) {
                    #pragma unroll
                    for (int r = 0; r < 4; ++r)
                        D[r] += BI[16 * mt + 4 * g + r] + (mt < 8 ? BH[16 * mt + 4 * g + r] : 0.0f);
                }
                #pragma unroll
                for (int r = 0; r < 4; ++r)
                    Bsh[(16 * mt + 4 * g + r) * 40 + 16 * nt + i16] = (_Float16)D[r];
            }
        }
    }
    __syncthreads();   // only block barrier

    // ---- per-lane constants ----
    floatx4 bhn[4];
    #pragma unroll
    for (int mt = 0; mt < 4; ++mt) {
        floatx4 v;
        #pragma unroll
        for (int r = 0; r < 4; ++r) v[r] = BH[128 + 16 * mt + 4 * g + r];
        bhn[mt] = v;
    }
    float twc[8], tbc[8];
    #pragma unroll
    for (int j = 0; j < 8; ++j) {
        twc[j] = time_w[8 * (g & 1) + j];
        tbc[j] = time_b[8 * (g & 1) + j];
    }
    const int* pn = (is_src ? s_nids : d_nids) + (size_t)b * NN;
    const int* pe = (is_src ? s_eids : d_eids) + (size_t)b * NN;
    const float* pt = (is_src ? s_ts : d_ts) + (size_t)b * NN;
    const float tqL = times[b];
    const int didL = dst_ids[b];
    const int oid = is_src ? didL : src_ids[b];
    const float dskill = is_src ? nodef[(size_t)didL * 64] : 0.0f;

    _Float16* hb = hbuf + wave * (16 * 72);

    // ---- prime state for steps 0,1 ----
    int nidS[2]; float tsS[2], e0S[2], nskS[2];
    uint4 nf0S[2], nf1S[2];
    #pragma unroll
    for (int s = 0; s < 2; ++s) {
        nidS[s] = pn[s]; tsS[s] = pt[s];
        e0S[s] = edgef[4 * (size_t)pe[s]];
        nskS[s] = 0.0f; nf0S[s] = make_uint4(0,0,0,0); nf1S[s] = make_uint4(0,0,0,0);
        if (is_src) {
            const float* rp = nodef + (size_t)nidS[s] * 64 + 8 * g;
            float4 a = *(const float4*)rp,        c = *(const float4*)(rp + 4);
            float4 d = *(const float4*)(rp + 32), e = *(const float4*)(rp + 36);
            nskS[s] = __shfl(a.x, i16);
            nf0S[s] = make_uint4(pk2u(a.x,a.y), pk2u(a.z,a.w), pk2u(c.x,c.y), pk2u(c.z,c.w));
            nf1S[s] = make_uint4(pk2u(d.x,d.y), pk2u(d.z,d.w), pk2u(e.x,e.y), pk2u(e.z,e.w));
        }
    }

    floatx4 hM[4] = {{0,0,0,0},{0,0,0,0},{0,0,0,0},{0,0,0,0}};

    for (int tb = 0; tb < 25; ++tb) {
        // ---- (1) issue raw loads for steps 2tb+2, 2tb+3 ----
        int nidN[2] = {0, 0}; float tsN[2] = {0, 0}, e0N[2] = {0, 0};
        float4 ra[2], rb[2], rc[2], rd[2];
        const bool pf = (tb < 24);
        if (pf) {
            #pragma unroll
            for (int s = 0; s < 2; ++s) {
                int t2 = 2 * tb + 2 + s;
                nidN[s] = pn[t2]; tsN[s] = pt[t2];
                e0N[s] = edgef[4 * (size_t)pe[t2]];
                if (is_src) {
                    const float* rp = nodef + (size_t)nidN[s] * 64 + 8 * g;
                    ra[s] = *(const float4*)rp;        rb[s] = *(const float4*)(rp + 4);
                    rc[s] = *(const float4*)(rp + 32); rd[s] = *(const float4*)(rp + 36);
                }
            }
        }

        // ---- (2) gi-phase for steps 2tb, 2tb+1 ----
        uint4 tv[2];
        #pragma unroll
        for (int s = 0; s < 2; ++s) {
            float sf = ((nidS[s] == oid) ? 1.0f : 0.0f) +
                       ((is_src && nskS[s] == dskill) ? 1.0f : 0.0f);
            float delta = tqL - tsS[s];
            if (g < 2) {
                float cv[8];
                #pragma unroll
                for (int j = 0; j < 8; ++j) cv[j] = __cosf(delta * twc[j] + tbc[j]);
                tv[s] = make_uint4(pk2u(cv[0],cv[1]), pk2u(cv[2],cv[3]), pk2u(cv[4],cv[5]), pk2u(cv[6],cv[7]));
            } else if (g == 2) {
                tv[s] = make_uint4(pk2u(e0S[s], sf), pk2u(1.0f, 0.0f), 0u, 0u);
            } else {
                tv[s] = make_uint4(0u, 0u, 0u, 0u);
            }
        }
        uint2 giP[2][12];
        #pragma unroll
        for (int mt = 0; mt < 12; ++mt) {
            uint4 BA = *(const uint4*)&Bsh[(16 * mt + i16) * 40 + 8 * g];
            floatx4 a0 = MFMA(u2h(BA), u2h(tv[0]), z4);
            floatx4 a1 = MFMA(u2h(BA), u2h(tv[1]), z4);
            if (is_src) {
                uint4 G0 = *(const uint4*)&Gsh[(16 * mt + i16) * 72 + 8 * g];
                uint4 G1 = *(const uint4*)&Gsh[(16 * mt + i16) * 72 + 32 + 8 * g];
                a0 = MFMA(u2h(G0), u2h(nf0S[0]), a0);
                a0 = MFMA(u2h(G1), u2h(nf1S[0]), a0);
                a1 = MFMA(u2h(G0), u2h(nf0S[1]), a1);
                a1 = MFMA(u2h(G1), u2h(nf1S[1]), a1);
            }
            giP[0][mt] = pkx4(a0);
            giP[1][mt] = pkx4(a1);
        }

        // ---- (3) pack next state (loads have had the gi-phase to land) ----
        if (pf) {
            #pragma unroll
            for (int s = 0; s < 2; ++s) {
                nidS[s] = nidN[s]; tsS[s] = tsN[s]; e0S[s] = e0N[s];
                if (is_src) {
                    nskS[s] = __shfl(ra[s].x, i16);
                    nf0S[s] = make_uint4(pk2u(ra[s].x,ra[s].y), pk2u(ra[s].z,ra[s].w),
                                         pk2u(rb[s].x,rb[s].y), pk2u(rb[s].z,rb[s].w));
                    nf1S[s] = make_uint4(pk2u(rc[s].x,rc[s].y), pk2u(rc[s].z,rc[s].w),
                                         pk2u(rd[s].x,rd[s].y), pk2u(rd[s].z,rd[s].w));
                }
            }
        }

        // ---- (4) serial GRU steps ----
        #pragma unroll
        for (int s = 0; s < 2; ++s) {
            half8 hB0 = u2h(*(const uint4*)&hb[i16 * 72 + 8 * g]);
            half8 hB1 = u2h(*(const uint4*)&hb[i16 * 72 + 32 + 8 * g]);
            floatx4 ga[12];
            #pragma unroll
            for (int mt = 0; mt < 8; ++mt) {
                floatx4 c = up4(giP[s][mt]);
                c = MFMA(u2h(whh[mt][0]), hB0, c);
                ga[mt] = MFMA(u2h(whh[mt][1]), hB1, c);
            }
            #pragma unroll
            for (int mt = 8; mt < 12; ++mt) {
                floatx4 c = MFMA(u2h(whh[mt][0]), hB0, bhn[mt - 8]);
                ga[mt] = MFMA(u2h(whh[mt][1]), hB1, c);
            }
            #pragma unroll
            for (int mt = 0; mt < 4; ++mt) {
                floatx4 gin = up4(giP[s][8 + mt]);
                #pragma unroll
                for (int r = 0; r < 4; ++r) {
                    float rr = fsig(ga[mt][r]);
                    float zz = fsig(ga[4 + mt][r]);
                    float nn = ftanhf(gin[r] + rr * ga[8 + mt][r]);
                    hM[mt][r] = nn + zz * (hM[mt][r] - nn);
                }
            }
            #pragma unroll
            for (int mt = 0; mt < 4; ++mt)
                *(uint2*)&hb[i16 * 72 + 16 * mt + 4 * g] = pkx4(hM[mt]);
        }
    }

    // ---- tail: time(delta=0) + edge(eid 0) [+ node_f(did) + b_feat for dst] ----
    float e00 = edgef[0];
    uint4 tt4;
    if (g < 2) {
        float cv[8];
        #pragma unroll
        for (int j = 0; j < 8; ++j) cv[j] = __cosf(tbc[j]);
        tt4 = make_uint4(pk2u(cv[0],cv[1]), pk2u(cv[2],cv[3]), pk2u(cv[4],cv[5]), pk2u(cv[6],cv[7]));
    } else if (g == 2) {
        tt4 = make_uint4(pk2u(e00, 0.0f), pk2u(1.0f, 0.0f), pk2u(is_src ? 0.0f : 1.0f, 0.0f), 0u);
    } else {
        tt4 = make_uint4(0u, 0u, 0u, 0u);
    }
    half8 tT = u2h(tt4);

    floatx4 tacc[4];
    #pragma unroll
    for (int mt = 0; mt < 4; ++mt) tacc[mt] = MFMA(u2h(wtT[mt][lane]), tT, z4);
    if (!is_src) {
        const float* rp = nodef + (size_t)didL * 64 + 8 * g;
        float4 a = *(const float4*)rp,        c = *(const float4*)(rp + 4);
        float4 d = *(const float4*)(rp + 32), e = *(const float4*)(rp + 36);
        uint4 d0 = make_uint4(pk2u(a.x,a.y), pk2u(a.z,a.w), pk2u(c.x,c.y), pk2u(c.z,c.w));
        uint4 d1 = make_uint4(pk2u(d.x,d.y), pk2u(d.z,d.w), pk2u(e.x,e.y), pk2u(e.z,e.w));
        #pragma unroll
        for (int mt = 0; mt < 4; ++mt) {
            uint4 G0 = *(const uint4*)&Gsh[(16 * mt + i16) * 72 + 8 * g];
            uint4 G1 = *(const uint4*)&Gsh[(16 * mt + i16) * 72 + 32 + 8 * g];
            tacc[mt] = MFMA(u2h(G0), u2h(d0), tacc[mt]);
            tacc[mt] = MFMA(u2h(G1), u2h(d1), tacc[mt]);
        }
    }

    // ---- out = (h + tail) @ W_out + b_out ----
    #pragma unroll
    for (int mt = 0; mt < 4; ++mt) {
        floatx4 e4 = hM[mt] + tacc[mt];
        *(uint2*)&hb[i16 * 72 + 16 * mt + 4 * g] = pkx4(e4);
    }
    half8 eB0 = u2h(*(const uint4*)&hb[i16 * 72 + 8 * g]);
    half8 eB1 = u2h(*(const uint4*)&hb[i16 * 72 + 32 + 8 * g]);

    const size_t obase = (is_src ? 0 : (size_t)BB * 64) + (size_t)(ib0 + i16) * 64;
    #pragma unroll
    for (int mt = 0; mt < 4; ++mt) {
        floatx4 bo;
        #pragma unroll
        for (int r = 0; r < 4; ++r) bo[r] = b_out[16 * mt + 4 * g + r];
        floatx4 o = MFMA(u2h(woA[mt][lane]), eB0, bo);
        o = MFMA(u2h(woA[4 + mt][lane]), eB1, o);
        #pragma unroll
        for (int r = 0; r < 4; ++r)
            out[obase + 16 * mt + 4 * g + r] = o[r];
    }
}

extern "C" void kernel_launch(void* const* d_in, const int* in_sizes, int n_in,
                              void* d_out, int out_size, void* d_ws, size_t ws_size,
                              hipStream_t stream) {
    (void)in_sizes; (void)n_in; (void)d_ws; (void)ws_size; (void)out_size;
    const float* nodef  = (const float*)d_in[0];
    const float* edgef  = (const float*)d_in[1];
    const int*   srcid  = (const int*)  d_in[2];
    const int*   dstid  = (const int*)  d_in[3];
    const float* times  = (const float*)d_in[4];
    const int*   s_nids = (const int*)  d_in[5];
    const int*   s_eids = (const int*)  d_in[6];
    const float* s_ts   = (const float*)d_in[7];
    const int*   d_nids = (const int*)  d_in[8];
    const int*   d_eids = (const int*)  d_in[9];
    const float* d_ts   = (const float*)d_in[10];
    const float* W_feat = (const float*)d_in[11];
    const float* b_feat = (const float*)d_in[12];
    const float* W_edge = (const float*)d_in[13];
    const float* b_edge = (const float*)d_in[14];
    const float* W_time = (const float*)d_in[15];
    const float* b_time = (const float*)d_in[16];
    const float* W_str  = (const float*)d_in[17];
    const float* b_str  = (const float*)d_in[18];
    const float* W_out  = (const float*)d_in[19];
    const float* b_out  = (const float*)d_in[20];
    const float* time_w = (const float*)d_in[21];
    const float* time_b = (const float*)d_in[22];
    const float* sWih   = (const float*)d_in[23];
    const float* sWhh   = (const float*)d_in[24];
    const float* sbih   = (const float*)d_in[25];
    const float* sbhh   = (const float*)d_in[26];
    const float* dWih   = (const float*)d_in[27];
    const float* dWhh   = (const float*)d_in[28];
    const float* dbih   = (const float*)d_in[29];
    const float* dbhh   = (const float*)d_in[30];

    dim3 grid(256), block(256);
    dygkt4<<<grid, block, 0, stream>>>(
        nodef, edgef, srcid, dstid, times,
        s_nids, s_eids, s_ts, d_nids, d_eids, d_ts,
        W_feat, b_feat, W_edge, b_edge, W_time, b_time,
        W_str, b_str, W_out, b_out, time_w, time_b,
        sWih, sWhh, sbih, sbhh, dWih, dWhh, dbih, dbhh,
        (float*)d_out);
}

// Round 5
// 303.988 us; speedup vs baseline: 1.1542x; 1.1542x over previous
//
#include <hip/hip_runtime.h>
#include <stdint.h>

#define BB 8192
#define NN 50

typedef _Float16 half8 __attribute__((ext_vector_type(8)));
typedef _Float16 half4v __attribute__((ext_vector_type(4)));
typedef float floatx4 __attribute__((ext_vector_type(4)));

union FragU { uint4 u; half8 h; };
static __device__ __forceinline__ half8 u2h(uint4 u) { FragU f; f.u = u; return f.h; }
union F2U { uint2 u; half4v h; };
static __device__ __forceinline__ floatx4 up4(uint2 u) {
    F2U f; f.u = u; floatx4 r;
    r[0] = (float)f.h[0]; r[1] = (float)f.h[1]; r[2] = (float)f.h[2]; r[3] = (float)f.h[3];
    return r;
}
static __device__ __forceinline__ uint32_t pk2u(float a, float b) {
    auto p = __builtin_amdgcn_cvt_pkrtz(a, b);
    uint32_t u; __builtin_memcpy(&u, &p, 4); return u;
}
static __device__ __forceinline__ uint2 pkx4(floatx4 v) {
    return make_uint2(pk2u(v[0], v[1]), pk2u(v[2], v[3]));
}
static __device__ __forceinline__ uint4 pkf8(const float* p) {
    float4 a = *(const float4*)p, b = *(const float4*)(p + 4);
    return make_uint4(pk2u(a.x, a.y), pk2u(a.z, a.w), pk2u(b.x, b.y), pk2u(b.z, b.w));
}
#define MFMA(A, B, C) __builtin_amdgcn_mfma_f32_16x16x32_f16((A), (B), (C), 0, 0, 0)
static __device__ __forceinline__ float fsig(float x)   { return 1.0f / (1.0f + __expf(-x)); }
static __device__ __forceinline__ float ftanhf(float x) { return 1.0f - 2.0f / (__expf(2.0f * x) + 1.0f); }

// Producer/consumer wave specialization. 512 blocks x 256 thr; blocks 0..255 src, 256..511 dst.
// Block = 2 chains x {producer wave, consumer wave}. Producer streams gi(t) (h-independent
// GEMMs + gathers) into a depth-2 LDS ring; consumer runs the serial GRU (W_hh in 96 VGPRs).
// 2048 waves -> 2 waves/SIMD: serial-chain latency hidden by co-resident waves.
__global__ __launch_bounds__(256, 2)
void dygkt5(const float* __restrict__ nodef, const float* __restrict__ edgef,
            const int* __restrict__ src_ids, const int* __restrict__ dst_ids,
            const float* __restrict__ times,
            const int* __restrict__ s_nids, const int* __restrict__ s_eids,
            const float* __restrict__ s_ts,
            const int* __restrict__ d_nids, const int* __restrict__ d_eids,
            const float* __restrict__ d_ts,
            const float* __restrict__ W_feat, const float* __restrict__ b_feat,
            const float* __restrict__ W_edge, const float* __restrict__ b_edge,
            const float* __restrict__ W_time, const float* __restrict__ b_time,
            const float* __restrict__ W_str,  const float* __restrict__ b_str,
            const float* __restrict__ W_out,  const float* __restrict__ b_out,
            const float* __restrict__ time_w, const float* __restrict__ time_b,
            const float* __restrict__ sWih, const float* __restrict__ sWhh,
            const float* __restrict__ sbih, const float* __restrict__ sbhh,
            const float* __restrict__ dWih, const float* __restrict__ dWhh,
            const float* __restrict__ dbih, const float* __restrict__ dbhh,
            float* __restrict__ out)
{
    __shared__ _Float16 Gsh[192 * 72];      // 27648 B: G (src) / W_feat^T (dst)
    __shared__ uint4    ring[2][2][6][64];  // 24576 B: [chain][slot][tilepair][lane]
    __shared__ uint4    woA[8][64];         //  8192 B: W_out^T A-frags
    __shared__ _Float16 hbuf[2][16 * 72];   //  4608 B: per-chain h^T staging
    __shared__ unsigned pcnt[2];            // producer progress (steps done)
    __shared__ unsigned ccnt[2];            // consumer progress (steps consumed)
    // total 65040 B

    const int tid = threadIdx.x, wave = tid >> 6, lane = tid & 63;
    const int g = lane >> 4, i16 = lane & 15;
    const int chain = wave >> 1;
    const bool is_prod = (wave & 1) == 0;
    const bool is_src = blockIdx.x < 256;
    const int ib0 = (int)(blockIdx.x & 255) * 32 + chain * 16;
    const int b = ib0 + i16;
    const floatx4 z4 = {0, 0, 0, 0};

    const float* WI = is_src ? sWih : dWih;
    const float* WH = is_src ? sWhh : dWhh;
    const float* BI = is_src ? sbih : dbih;
    const float* BH = is_src ? sbhh : dbhh;

    volatile unsigned* vp = (volatile unsigned*)pcnt;
    volatile unsigned* vc = (volatile unsigned*)ccnt;

    // ---- stage W_out^T A-frags (all waves) ----
    for (int q = tid; q < 512; q += 256) {
        int l = q & 63, tt = q >> 6;
        int kh = tt >> 2, mt = tt & 3, gg = l >> 4, ii = l & 15;
        float w[8];
        #pragma unroll
        for (int j = 0; j < 8; ++j)
            w[j] = W_out[(32 * kh + 8 * gg + j) * 64 + 16 * mt + ii];
        woA[tt][l] = make_uint4(pk2u(w[0],w[1]), pk2u(w[2],w[3]), pk2u(w[4],w[5]), pk2u(w[6],w[7]));
    }
    // ---- G = Wih @ Wfeat^T (src, coop) / W_feat^T elementwise (dst) ----
    if (is_src) {
        for (int mt = wave; mt < 12; mt += 4) {
            uint4 A0 = pkf8(WI + (size_t)(16 * mt + i16) * 64 + 8 * g);
            uint4 A1 = pkf8(WI + (size_t)(16 * mt + i16) * 64 + 32 + 8 * g);
            #pragma unroll
            for (int nt = 0; nt < 4; ++nt) {
                uint4 B0 = pkf8(W_feat + (size_t)(16 * nt + i16) * 64 + 8 * g);
                uint4 B1 = pkf8(W_feat + (size_t)(16 * nt + i16) * 64 + 32 + 8 * g);
                floatx4 D = MFMA(u2h(A1), u2h(B1), MFMA(u2h(A0), u2h(B0), z4));
                #pragma unroll
                for (int r = 0; r < 4; ++r)
                    Gsh[(16 * mt + 4 * g + r) * 72 + 16 * nt + i16] = (_Float16)D[r];
            }
        }
    } else {
        for (int p = tid; p < 4096; p += 256) {
            int m = p & 63, j = p >> 6;
            Gsh[m * 72 + j] = (_Float16)W_feat[j * 64 + m];
        }
    }
    if (tid < 2) { pcnt[tid] = 0; ccnt[tid] = 0; }
    __syncthreads();   // only block barrier

    if (is_prod) {
        // ================= PRODUCER =================
        // Bu = Wih @ [time|edge|struct|bias] via MFMA, relayout through ring temp -> 12 A-frag regs
        _Float16* Bt = (_Float16*)&ring[chain][0][0][0];   // 12288 B wave-private temp
        for (int mt = 0; mt < 12; ++mt) {
            uint4 A0 = pkf8(WI + (size_t)(16 * mt + i16) * 64 + 8 * g);
            uint4 A1 = pkf8(WI + (size_t)(16 * mt + i16) * 64 + 32 + 8 * g);
            #pragma unroll
            for (int nt = 0; nt < 2; ++nt) {
                uint4 bB[2];
                #pragma unroll
                for (int kh = 0; kh < 2; ++kh) {
                    float v[8];
                    #pragma unroll
                    for (int jj = 0; jj < 8; ++jj) {
                        int d = 32 * kh + 8 * g + jj;
                        float x = 0.0f;
                        if (nt == 0) x = W_time[i16 * 64 + d];
                        else if (i16 == 0) x = W_edge[d];
                        else if (i16 == 1) x = W_str[d];
                        else if (i16 == 2) x = is_src ? (b_edge[d] + b_time[d] + b_feat[d] + 2.0f * b_str[d])
                                                      : (b_edge[d] + b_time[d] + b_str[d]);
                        v[jj] = x;
                    }
                    bB[kh] = make_uint4(pk2u(v[0],v[1]), pk2u(v[2],v[3]), pk2u(v[4],v[5]), pk2u(v[6],v[7]));
                }
                floatx4 D = MFMA(u2h(A1), u2h(bB[1]), MFMA(u2h(A0), u2h(bB[0]), z4));
                if (nt == 1 && i16 == 2) {
                    #pragma unroll
                    for (int r = 0; r < 4; ++r)
                        D[r] += BI[16 * mt + 4 * g + r] + (mt < 8 ? BH[16 * mt + 4 * g + r] : 0.0f);
                }
                #pragma unroll
                for (int r = 0; r < 4; ++r)
                    Bt[(16 * mt + 4 * g + r) * 32 + 16 * nt + i16] = (_Float16)D[r];
            }
        }
        uint4 Bur[12];
        #pragma unroll
        for (int mt = 0; mt < 12; ++mt)
            Bur[mt] = *(const uint4*)&Bt[(16 * mt + i16) * 32 + 8 * g];

        // per-item scalars
        const int* pn = (is_src ? s_nids : d_nids) + (size_t)b * NN;
        const int* pe = (is_src ? s_eids : d_eids) + (size_t)b * NN;
        const float* pt = (is_src ? s_ts : d_ts) + (size_t)b * NN;
        const float tqL = times[b];
        const int didL = dst_ids[b];
        const int oid = is_src ? didL : src_ids[b];
        const float dskill = is_src ? nodef[(size_t)didL * 64] : 0.0f;
        float twc[8], tbc[8];
        #pragma unroll
        for (int j = 0; j < 8; ++j) {
            twc[j] = time_w[8 * (g & 1) + j];
            tbc[j] = time_b[8 * (g & 1) + j];
        }

        // prime state for steps 0,1
        int nidS[2]; float tsS[2], e0S[2], nskS[2];
        uint4 nf0S[2], nf1S[2];
        #pragma unroll
        for (int s = 0; s < 2; ++s) {
            nidS[s] = pn[s]; tsS[s] = pt[s];
            e0S[s] = edgef[4 * (size_t)pe[s]];
            nskS[s] = 0.0f; nf0S[s] = make_uint4(0,0,0,0); nf1S[s] = make_uint4(0,0,0,0);
            if (is_src) {
                const float* rp = nodef + (size_t)nidS[s] * 64 + 8 * g;
                float4 a = *(const float4*)rp,        c = *(const float4*)(rp + 4);
                float4 d = *(const float4*)(rp + 32), e = *(const float4*)(rp + 36);
                nskS[s] = __shfl(a.x, i16);
                nf0S[s] = make_uint4(pk2u(a.x,a.y), pk2u(a.z,a.w), pk2u(c.x,c.y), pk2u(c.z,c.w));
                nf1S[s] = make_uint4(pk2u(d.x,d.y), pk2u(d.z,d.w), pk2u(e.x,e.y), pk2u(e.z,e.w));
            }
        }

        for (int tb = 0; tb < 25; ++tb) {
            // (1) prefetch steps 2tb+2, 2tb+3
            int nidN[2] = {0, 0}; float tsN[2] = {0, 0}, e0N[2] = {0, 0};
            float4 ra[2], rb[2], rc[2], rd[2];
            const bool pf = (tb < 24);
            if (pf) {
                #pragma unroll
                for (int s = 0; s < 2; ++s) {
                    int t2 = 2 * tb + 2 + s;
                    nidN[s] = pn[t2]; tsN[s] = pt[t2];
                    e0N[s] = edgef[4 * (size_t)pe[t2]];
                    if (is_src) {
                        const float* rp = nodef + (size_t)nidN[s] * 64 + 8 * g;
                        ra[s] = *(const float4*)rp;        rb[s] = *(const float4*)(rp + 4);
                        rc[s] = *(const float4*)(rp + 32); rd[s] = *(const float4*)(rp + 36);
                    }
                }
            }

            // (2) gi for steps 2tb, 2tb+1
            uint4 tv[2];
            #pragma unroll
            for (int s = 0; s < 2; ++s) {
                float sf = ((nidS[s] == oid) ? 1.0f : 0.0f) +
                           ((is_src && nskS[s] == dskill) ? 1.0f : 0.0f);
                float delta = tqL - tsS[s];
                if (g < 2) {
                    float cv[8];
                    #pragma unroll
                    for (int j = 0; j < 8; ++j) cv[j] = __cosf(delta * twc[j] + tbc[j]);
                    tv[s] = make_uint4(pk2u(cv[0],cv[1]), pk2u(cv[2],cv[3]), pk2u(cv[4],cv[5]), pk2u(cv[6],cv[7]));
                } else if (g == 2) {
                    tv[s] = make_uint4(pk2u(e0S[s], sf), pk2u(1.0f, 0.0f), 0u, 0u);
                } else {
                    tv[s] = make_uint4(0u, 0u, 0u, 0u);
                }
            }
            uint2 q0[12], q1[12];
            #pragma unroll
            for (int mt = 0; mt < 12; ++mt) {
                floatx4 a0 = MFMA(u2h(Bur[mt]), u2h(tv[0]), z4);
                floatx4 a1 = MFMA(u2h(Bur[mt]), u2h(tv[1]), z4);
                if (is_src) {
                    uint4 G0 = *(const uint4*)&Gsh[(16 * mt + i16) * 72 + 8 * g];
                    uint4 G1 = *(const uint4*)&Gsh[(16 * mt + i16) * 72 + 32 + 8 * g];
                    a0 = MFMA(u2h(G0), u2h(nf0S[0]), a0);
                    a0 = MFMA(u2h(G1), u2h(nf1S[0]), a0);
                    a1 = MFMA(u2h(G0), u2h(nf0S[1]), a1);
                    a1 = MFMA(u2h(G1), u2h(nf1S[1]), a1);
                }
                q0[mt] = pkx4(a0);
                q1[mt] = pkx4(a1);
            }

            // (3) wait for ring slots, publish both steps
            while (vc[chain] < (unsigned)(2 * tb)) __builtin_amdgcn_s_sleep(1);
            #pragma unroll
            for (int k = 0; k < 6; ++k) {
                ring[chain][0][k][lane] = make_uint4(q0[2*k].x, q0[2*k].y, q0[2*k+1].x, q0[2*k+1].y);
                ring[chain][1][k][lane] = make_uint4(q1[2*k].x, q1[2*k].y, q1[2*k+1].x, q1[2*k+1].y);
            }
            __threadfence_block();
            if (lane == 0) vp[chain] = (unsigned)(2 * tb + 2);

            // (4) advance state
            if (pf) {
                #pragma unroll
                for (int s = 0; s < 2; ++s) {
                    nidS[s] = nidN[s]; tsS[s] = tsN[s]; e0S[s] = e0N[s];
                    if (is_src) {
                        nskS[s] = __shfl(ra[s].x, i16);
                        nf0S[s] = make_uint4(pk2u(ra[s].x,ra[s].y), pk2u(ra[s].z,ra[s].w),
                                             pk2u(rb[s].x,rb[s].y), pk2u(rb[s].z,rb[s].w));
                        nf1S[s] = make_uint4(pk2u(rc[s].x,rc[s].y), pk2u(rc[s].z,rc[s].w),
                                             pk2u(rd[s].x,rd[s].y), pk2u(rd[s].z,rd[s].w));
                    }
                }
            }
        }
    } else {
        // ================= CONSUMER =================
        uint4 whh[12][2];
        #pragma unroll
        for (int mt = 0; mt < 12; ++mt)
            #pragma unroll
            for (int kh = 0; kh < 2; ++kh)
                whh[mt][kh] = pkf8(WH + (size_t)(16 * mt + i16) * 64 + 32 * kh + 8 * g);
        floatx4 bhn[4];
        #pragma unroll
        for (int mt = 0; mt < 4; ++mt) {
            floatx4 v;
            #pragma unroll
            for (int r = 0; r < 4; ++r) v[r] = BH[128 + 16 * mt + 4 * g + r];
            bhn[mt] = v;
        }
        _Float16* hb = hbuf[chain];
        for (int q = lane; q < 576; q += 64) ((uint32_t*)hb)[q] = 0u;

        floatx4 hM[4] = {{0,0,0,0},{0,0,0,0},{0,0,0,0},{0,0,0,0}};

        for (int t = 0; t < NN; ++t) {
            while (vp[chain] < (unsigned)(t + 1)) __builtin_amdgcn_s_sleep(1);
            __threadfence_block();
            const int sl = t & 1;
            uint4 u0 = ring[chain][sl][0][lane], u1 = ring[chain][sl][1][lane];
            uint4 u2 = ring[chain][sl][2][lane], u3 = ring[chain][sl][3][lane];
            uint4 u4 = ring[chain][sl][4][lane], u5 = ring[chain][sl][5][lane];
            floatx4 gi[12];
            gi[0]  = up4(make_uint2(u0.x, u0.y)); gi[1]  = up4(make_uint2(u0.z, u0.w));
            gi[2]  = up4(make_uint2(u1.x, u1.y)); gi[3]  = up4(make_uint2(u1.z, u1.w));
            gi[4]  = up4(make_uint2(u2.x, u2.y)); gi[5]  = up4(make_uint2(u2.z, u2.w));
            gi[6]  = up4(make_uint2(u3.x, u3.y)); gi[7]  = up4(make_uint2(u3.z, u3.w));
            gi[8]  = up4(make_uint2(u4.x, u4.y)); gi[9]  = up4(make_uint2(u4.z, u4.w));
            gi[10] = up4(make_uint2(u5.x, u5.y)); gi[11] = up4(make_uint2(u5.z, u5.w));
            __threadfence_block();
            if (lane == 0) vc[chain] = (unsigned)(t + 1);

            half8 hB0 = u2h(*(const uint4*)&hb[i16 * 72 + 8 * g]);
            half8 hB1 = u2h(*(const uint4*)&hb[i16 * 72 + 32 + 8 * g]);
            floatx4 ga[12];
            #pragma unroll
            for (int mt = 0; mt < 8; ++mt) {
                floatx4 c = MFMA(u2h(whh[mt][0]), hB0, gi[mt]);
                ga[mt] = MFMA(u2h(whh[mt][1]), hB1, c);
            }
            #pragma unroll
            for (int mt = 8; mt < 12; ++mt) {
                floatx4 c = MFMA(u2h(whh[mt][0]), hB0, bhn[mt - 8]);
                ga[mt] = MFMA(u2h(whh[mt][1]), hB1, c);
            }
            #pragma unroll
            for (int mt = 0; mt < 4; ++mt) {
                #pragma unroll
                for (int r = 0; r < 4; ++r) {
                    float rr = fsig(ga[mt][r]);
                    float zz = fsig(ga[4 + mt][r]);
                    float nn = ftanhf(gi[8 + mt][r] + rr * ga[8 + mt][r]);
                    hM[mt][r] = nn + zz * (hM[mt][r] - nn);
                }
            }
            #pragma unroll
            for (int mt = 0; mt < 4; ++mt)
                *(uint2*)&hb[i16 * 72 + 16 * mt + 4 * g] = pkx4(hM[mt]);
        }

        // ---- tail ----
        float twc[8], tbc[8];
        #pragma unroll
        for (int j = 0; j < 8; ++j) {
            twc[j] = time_w[8 * (g & 1) + j];
            tbc[j] = time_b[8 * (g & 1) + j];
        }
        const int didL = dst_ids[b];
        float e00 = edgef[0];
        uint4 wtTr[4];
        #pragma unroll
        for (int mt = 0; mt < 4; ++mt) {
            float v[8];
            #pragma unroll
            for (int j = 0; j < 8; ++j) {
                int k = 8 * g + j, dim = 16 * mt + i16;
                float x = 0.0f;
                if (k < 16)       x = W_time[k * 64 + dim];
                else if (k == 16) x = W_edge[dim];
                else if (k == 17) x = W_str[dim];
                else if (k == 18) x = b_edge[dim] + b_time[dim];
                else if (k == 20) x = b_feat[dim];
                v[j] = x;
            }
            wtTr[mt] = make_uint4(pk2u(v[0],v[1]), pk2u(v[2],v[3]), pk2u(v[4],v[5]), pk2u(v[6],v[7]));
        }
        uint4 tt4;
        if (g < 2) {
            float cv[8];
            #pragma unroll
            for (int j = 0; j < 8; ++j) cv[j] = __cosf(tbc[j]);
            tt4 = make_uint4(pk2u(cv[0],cv[1]), pk2u(cv[2],cv[3]), pk2u(cv[4],cv[5]), pk2u(cv[6],cv[7]));
        } else if (g == 2) {
            tt4 = make_uint4(pk2u(e00, 0.0f), pk2u(1.0f, 0.0f), pk2u(is_src ? 0.0f : 1.0f, 0.0f), 0u);
        } else {
            tt4 = make_uint4(0u, 0u, 0u, 0u);
        }
        half8 tT = u2h(tt4);

        floatx4 tacc[4];
        #pragma unroll
        for (int mt = 0; mt < 4; ++mt) tacc[mt] = MFMA(u2h(wtTr[mt]), tT, z4);
        if (!is_src) {
            const float* rp = nodef + (size_t)didL * 64 + 8 * g;
            float4 a = *(const float4*)rp,        c = *(const float4*)(rp + 4);
            float4 d = *(const float4*)(rp + 32), e = *(const float4*)(rp + 36);
            uint4 d0 = make_uint4(pk2u(a.x,a.y), pk2u(a.z,a.w), pk2u(c.x,c.y), pk2u(c.z,c.w));
            uint4 d1 = make_uint4(pk2u(d.x,d.y), pk2u(d.z,d.w), pk2u(e.x,e.y), pk2u(e.z,e.w));
            #pragma unroll
            for (int mt = 0; mt < 4; ++mt) {
                uint4 G0 = *(const uint4*)&Gsh[(16 * mt + i16) * 72 + 8 * g];
                uint4 G1 = *(const uint4*)&Gsh[(16 * mt + i16) * 72 + 32 + 8 * g];
                tacc[mt] = MFMA(u2h(G0), u2h(d0), tacc[mt]);
                tacc[mt] = MFMA(u2h(G1), u2h(d1), tacc[mt]);
            }
        }

        #pragma unroll
        for (int mt = 0; mt < 4; ++mt) {
            floatx4 e4 = hM[mt] + tacc[mt];
            *(uint2*)&hb[i16 * 72 + 16 * mt + 4 * g] = pkx4(e4);
        }
        half8 eB0 = u2h(*(const uint4*)&hb[i16 * 72 + 8 * g]);
        half8 eB1 = u2h(*(const uint4*)&hb[i16 * 72 + 32 + 8 * g]);

        const size_t obase = (is_src ? 0 : (size_t)BB * 64) + (size_t)(ib0 + i16) * 64;
        #pragma unroll
        for (int mt = 0; mt < 4; ++mt) {
            floatx4 bo;
            #pragma unroll
            for (int r = 0; r < 4; ++r) bo[r] = b_out[16 * mt + 4 * g + r];
            floatx4 o = MFMA(u2h(woA[mt][lane]), eB0, bo);
            o = MFMA(u2h(woA[4 + mt][lane]), eB1, o);
            #pragma unroll
            for (int r = 0; r < 4; ++r)
                out[obase + 16 * mt + 4 * g + r] = o[r];
        }
    }
}

extern "C" void kernel_launch(void* const* d_in, const int* in_sizes, int n_in,
                              void* d_out, int out_size, void* d_ws, size_t ws_size,
                              hipStream_t stream) {
    (void)in_sizes; (void)n_in; (void)d_ws; (void)ws_size; (void)out_size;
    const float* nodef  = (const float*)d_in[0];
    const float* edgef  = (const float*)d_in[1];
    const int*   srcid  = (const int*)  d_in[2];
    const int*   dstid  = (const int*)  d_in[3];
    const float* times  = (const float*)d_in[4];
    const int*   s_nids = (const int*)  d_in[5];
    const int*   s_eids = (const int*)  d_in[6];
    const float* s_ts   = (const float*)d_in[7];
    const int*   d_nids = (const int*)  d_in[8];
    const int*   d_eids = (const int*)  d_in[9];
    const float* d_ts   = (const float*)d_in[10];
    const float* W_feat = (const float*)d_in[11];
    const float* b_feat = (const float*)d_in[12];
    const float* W_edge = (const float*)d_in[13];
    const float* b_edge = (const float*)d_in[14];
    const float* W_time = (const float*)d_in[15];
    const float* b_time = (const float*)d_in[16];
    const float* W_str  = (const float*)d_in[17];
    const float* b_str  = (const float*)d_in[18];
    const float* W_out  = (const float*)d_in[19];
    const float* b_out  = (const float*)d_in[20];
    const float* time_w = (const float*)d_in[21];
    const float* time_b = (const float*)d_in[22];
    const float* sWih   = (const float*)d_in[23];
    const float* sWhh   = (const float*)d_in[24];
    const float* sbih   = (const float*)d_in[25];
    const float* sbhh   = (const float*)d_in[26];
    const float* dWih   = (const float*)d_in[27];
    const float* dWhh   = (const float*)d_in[28];
    const float* dbih   = (const float*)d_in[29];
    const float* dbhh   = (const float*)d_in[30];

    dim3 grid(512), block(256);
    dygkt5<<<grid, block, 0, stream>>>(
        nodef, edgef, srcid, dstid, times,
        s_nids, s_eids, s_ts, d_nids, d_eids, d_ts,
        W_feat, b_feat, W_edge, b_edge, W_time, b_time,
        W_str, b_str, W_out, b_out, time_w, time_b,
        sWih, sWhh, sbih, sbhh, dWih, dWhh, dbih, dbhh,
        (float*)d_out);
}

// Round 6
// 298.228 us; speedup vs baseline: 1.1765x; 1.0193x over previous
//
#include <hip/hip_runtime.h>
#include <stdint.h>
#include <math.h>

#define BB 8192
#define NN 50

typedef _Float16 half8 __attribute__((ext_vector_type(8)));
typedef _Float16 half4v __attribute__((ext_vector_type(4)));
typedef float floatx4 __attribute__((ext_vector_type(4)));

union FragU { uint4 u; half8 h; };
static __device__ __forceinline__ half8 u2h(uint4 u) { FragU f; f.u = u; return f.h; }
union F2U { uint2 u; half4v h; };
static __device__ __forceinline__ floatx4 up4(uint2 u) {
    F2U f; f.u = u; floatx4 r;
    r[0] = (float)f.h[0]; r[1] = (float)f.h[1]; r[2] = (float)f.h[2]; r[3] = (float)f.h[3];
    return r;
}
static __device__ __forceinline__ uint32_t pk2u(float a, float b) {
    auto p = __builtin_amdgcn_cvt_pkrtz(a, b);
    uint32_t u; __builtin_memcpy(&u, &p, 4); return u;
}
static __device__ __forceinline__ uint2 pkx4(floatx4 v) {
    return make_uint2(pk2u(v[0], v[1]), pk2u(v[2], v[3]));
}
static __device__ __forceinline__ uint4 pkf8(const float* p) {
    float4 a = *(const float4*)p, b = *(const float4*)(p + 4);
    return make_uint4(pk2u(a.x, a.y), pk2u(a.z, a.w), pk2u(b.x, b.y), pk2u(b.z, b.w));
}
#define MFMA(A, B, C) __builtin_amdgcn_mfma_f32_16x16x32_f16((A), (B), (C), 0, 0, 0)

// tanh via LDS table lerp: tab[i] = tanh((i-1024)/128), i in [0,2048).
// t = x*128+1024 pre-computed by caller (or x*64+1024 for tanh(x/2)).
static __device__ __forceinline__ float tlerp(const float* tab, float t) {
    t = fminf(fmaxf(t, 0.0f), 2046.0f);
    int i = (int)t;
    float f = t - (float)i;
    float y0 = tab[i], y1 = tab[i + 1];
    return fmaf(f, y1 - y0, y0);
}

// Producer/consumer wave specialization; gate nonlinearities via LDS table (no v_exp/v_rcp
// in the loop — trans pipe was the r3/r4/r5 ~180us floor: ~96 trans-insts/step @ ~64cyc).
// 512 blocks x 256 thr; blocks 0..255 src, 256..511 dst. Block = 2 chains x {P,C} waves.
__global__ __launch_bounds__(256, 2)
void dygkt6(const float* __restrict__ nodef, const float* __restrict__ edgef,
            const int* __restrict__ src_ids, const int* __restrict__ dst_ids,
            const float* __restrict__ times,
            const int* __restrict__ s_nids, const int* __restrict__ s_eids,
            const float* __restrict__ s_ts,
            const int* __restrict__ d_nids, const int* __restrict__ d_eids,
            const float* __restrict__ d_ts,
            const float* __restrict__ W_feat, const float* __restrict__ b_feat,
            const float* __restrict__ W_edge, const float* __restrict__ b_edge,
            const float* __restrict__ W_time, const float* __restrict__ b_time,
            const float* __restrict__ W_str,  const float* __restrict__ b_str,
            const float* __restrict__ W_out,  const float* __restrict__ b_out,
            const float* __restrict__ time_w, const float* __restrict__ time_b,
            const float* __restrict__ sWih, const float* __restrict__ sWhh,
            const float* __restrict__ sbih, const float* __restrict__ sbhh,
            const float* __restrict__ dWih, const float* __restrict__ dWhh,
            const float* __restrict__ dbih, const float* __restrict__ dbhh,
            float* __restrict__ out)
{
    __shared__ _Float16 Gsh[192 * 72];      // 27648 B: G (src) / W_feat^T (dst)
    __shared__ uint4    ring[2][2][6][64];  // 24576 B
    __shared__ _Float16 hbuf[2][16 * 72];   //  4608 B
    __shared__ float    ttab[2048];         //  8192 B tanh table
    __shared__ unsigned pcnt[2];
    __shared__ unsigned ccnt[2];
    // total 65040 B

    const int tid = threadIdx.x, wave = tid >> 6, lane = tid & 63;
    const int g = lane >> 4, i16 = lane & 15;
    const int chain = wave >> 1;
    const bool is_prod = (wave & 1) == 0;
    const bool is_src = blockIdx.x < 256;
    const int ib0 = (int)(blockIdx.x & 255) * 32 + chain * 16;
    const int b = ib0 + i16;
    const floatx4 z4 = {0, 0, 0, 0};

    const float* WI = is_src ? sWih : dWih;
    const float* WH = is_src ? sWhh : dWhh;
    const float* BI = is_src ? sbih : dbih;
    const float* BH = is_src ? sbhh : dbhh;

    volatile unsigned* vp = (volatile unsigned*)pcnt;
    volatile unsigned* vc = (volatile unsigned*)ccnt;

    // ---- tanh table (one-time; trans ops allowed here) ----
    for (int q = tid; q < 2048; q += 256)
        ttab[q] = tanhf((float)(q - 1024) * (1.0f / 128.0f));

    // ---- G = Wih @ Wfeat^T (src, coop) / W_feat^T elementwise (dst) ----
    if (is_src) {
        for (int mt = wave; mt < 12; mt += 4) {
            uint4 A0 = pkf8(WI + (size_t)(16 * mt + i16) * 64 + 8 * g);
            uint4 A1 = pkf8(WI + (size_t)(16 * mt + i16) * 64 + 32 + 8 * g);
            #pragma unroll
            for (int nt = 0; nt < 4; ++nt) {
                uint4 B0 = pkf8(W_feat + (size_t)(16 * nt + i16) * 64 + 8 * g);
                uint4 B1 = pkf8(W_feat + (size_t)(16 * nt + i16) * 64 + 32 + 8 * g);
                floatx4 D = MFMA(u2h(A1), u2h(B1), MFMA(u2h(A0), u2h(B0), z4));
                #pragma unroll
                for (int r = 0; r < 4; ++r)
                    Gsh[(16 * mt + 4 * g + r) * 72 + 16 * nt + i16] = (_Float16)D[r];
            }
        }
    } else {
        for (int p = tid; p < 4096; p += 256) {
            int m = p & 63, j = p >> 6;
            Gsh[m * 72 + j] = (_Float16)W_feat[j * 64 + m];
        }
    }
    if (tid < 2) { pcnt[tid] = 0; ccnt[tid] = 0; }
    __syncthreads();   // only block barrier

    if (is_prod) {
        // ================= PRODUCER =================
        _Float16* Bt = (_Float16*)&ring[chain][0][0][0];   // wave-private temp
        for (int mt = 0; mt < 12; ++mt) {
            uint4 A0 = pkf8(WI + (size_t)(16 * mt + i16) * 64 + 8 * g);
            uint4 A1 = pkf8(WI + (size_t)(16 * mt + i16) * 64 + 32 + 8 * g);
            #pragma unroll
            for (int nt = 0; nt < 2; ++nt) {
                uint4 bB[2];
                #pragma unroll
                for (int kh = 0; kh < 2; ++kh) {
                    float v[8];
                    #pragma unroll
                    for (int jj = 0; jj < 8; ++jj) {
                        int d = 32 * kh + 8 * g + jj;
                        float x = 0.0f;
                        if (nt == 0) x = W_time[i16 * 64 + d];
                        else if (i16 == 0) x = W_edge[d];
                        else if (i16 == 1) x = W_str[d];
                        else if (i16 == 2) x = is_src ? (b_edge[d] + b_time[d] + b_feat[d] + 2.0f * b_str[d])
                                                      : (b_edge[d] + b_time[d] + b_str[d]);
                        v[jj] = x;
                    }
                    bB[kh] = make_uint4(pk2u(v[0],v[1]), pk2u(v[2],v[3]), pk2u(v[4],v[5]), pk2u(v[6],v[7]));
                }
                floatx4 D = MFMA(u2h(A1), u2h(bB[1]), MFMA(u2h(A0), u2h(bB[0]), z4));
                if (nt == 1 && i16 == 2) {
                    #pragma unroll
                    for (int r = 0; r < 4; ++r)
                        D[r] += BI[16 * mt + 4 * g + r] + (mt < 8 ? BH[16 * mt + 4 * g + r] : 0.0f);
                }
                #pragma unroll
                for (int r = 0; r < 4; ++r)
                    Bt[(16 * mt + 4 * g + r) * 32 + 16 * nt + i16] = (_Float16)D[r];
            }
        }
        uint4 Bur[12];
        #pragma unroll
        for (int mt = 0; mt < 12; ++mt)
            Bur[mt] = *(const uint4*)&Bt[(16 * mt + i16) * 32 + 8 * g];

        const int* pn = (is_src ? s_nids : d_nids) + (size_t)b * NN;
        const int* pe = (is_src ? s_eids : d_eids) + (size_t)b * NN;
        const float* pt = (is_src ? s_ts : d_ts) + (size_t)b * NN;
        const float tqL = times[b];
        const int didL = dst_ids[b];
        const int oid = is_src ? didL : src_ids[b];
        const float dskill = is_src ? nodef[(size_t)didL * 64] : 0.0f;
        float twc[8], tbc[8];
        #pragma unroll
        for (int j = 0; j < 8; ++j) {
            twc[j] = time_w[8 * (g & 1) + j];
            tbc[j] = time_b[8 * (g & 1) + j];
        }

        int nidS[2]; float tsS[2], e0S[2], nskS[2];
        uint4 nf0S[2], nf1S[2];
        #pragma unroll
        for (int s = 0; s < 2; ++s) {
            nidS[s] = pn[s]; tsS[s] = pt[s];
            e0S[s] = edgef[4 * (size_t)pe[s]];
            nskS[s] = 0.0f; nf0S[s] = make_uint4(0,0,0,0); nf1S[s] = make_uint4(0,0,0,0);
            if (is_src) {
                const float* rp = nodef + (size_t)nidS[s] * 64 + 8 * g;
                float4 a = *(const float4*)rp,        c = *(const float4*)(rp + 4);
                float4 d = *(const float4*)(rp + 32), e = *(const float4*)(rp + 36);
                nskS[s] = __shfl(a.x, i16);
                nf0S[s] = make_uint4(pk2u(a.x,a.y), pk2u(a.z,a.w), pk2u(c.x,c.y), pk2u(c.z,c.w));
                nf1S[s] = make_uint4(pk2u(d.x,d.y), pk2u(d.z,d.w), pk2u(e.x,e.y), pk2u(e.z,e.w));
            }
        }

        for (int tb = 0; tb < 25; ++tb) {
            int nidN[2] = {0, 0}; float tsN[2] = {0, 0}, e0N[2] = {0, 0};
            float4 ra[2], rb[2], rc[2], rd[2];
            const bool pf = (tb < 24);
            if (pf) {
                #pragma unroll
                for (int s = 0; s < 2; ++s) {
                    int t2 = 2 * tb + 2 + s;
                    nidN[s] = pn[t2]; tsN[s] = pt[t2];
                    e0N[s] = edgef[4 * (size_t)pe[t2]];
                    if (is_src) {
                        const float* rp = nodef + (size_t)nidN[s] * 64 + 8 * g;
                        ra[s] = *(const float4*)rp;        rb[s] = *(const float4*)(rp + 4);
                        rc[s] = *(const float4*)(rp + 32); rd[s] = *(const float4*)(rp + 36);
                    }
                }
            }

            uint4 tv[2];
            #pragma unroll
            for (int s = 0; s < 2; ++s) {
                float sf = ((nidS[s] == oid) ? 1.0f : 0.0f) +
                           ((is_src && nskS[s] == dskill) ? 1.0f : 0.0f);
                float delta = tqL - tsS[s];
                if (g < 2) {
                    float cv[8];
                    #pragma unroll
                    for (int j = 0; j < 8; ++j) cv[j] = __cosf(delta * twc[j] + tbc[j]);
                    tv[s] = make_uint4(pk2u(cv[0],cv[1]), pk2u(cv[2],cv[3]), pk2u(cv[4],cv[5]), pk2u(cv[6],cv[7]));
                } else if (g == 2) {
                    tv[s] = make_uint4(pk2u(e0S[s], sf), pk2u(1.0f, 0.0f), 0u, 0u);
                } else {
                    tv[s] = make_uint4(0u, 0u, 0u, 0u);
                }
            }
            uint2 q0[12], q1[12];
            #pragma unroll
            for (int mt = 0; mt < 12; ++mt) {
                floatx4 a0 = MFMA(u2h(Bur[mt]), u2h(tv[0]), z4);
                floatx4 a1 = MFMA(u2h(Bur[mt]), u2h(tv[1]), z4);
                if (is_src) {
                    uint4 G0 = *(const uint4*)&Gsh[(16 * mt + i16) * 72 + 8 * g];
                    uint4 G1 = *(const uint4*)&Gsh[(16 * mt + i16) * 72 + 32 + 8 * g];
                    a0 = MFMA(u2h(G0), u2h(nf0S[0]), a0);
                    a0 = MFMA(u2h(G1), u2h(nf1S[0]), a0);
                    a1 = MFMA(u2h(G0), u2h(nf0S[1]), a1);
                    a1 = MFMA(u2h(G1), u2h(nf1S[1]), a1);
                }
                q0[mt] = pkx4(a0);
                q1[mt] = pkx4(a1);
            }

            while (vc[chain] < (unsigned)(2 * tb)) __builtin_amdgcn_s_sleep(1);
            #pragma unroll
            for (int k = 0; k < 6; ++k) {
                ring[chain][0][k][lane] = make_uint4(q0[2*k].x, q0[2*k].y, q0[2*k+1].x, q0[2*k+1].y);
                ring[chain][1][k][lane] = make_uint4(q1[2*k].x, q1[2*k].y, q1[2*k+1].x, q1[2*k+1].y);
            }
            __threadfence_block();
            if (lane == 0) vp[chain] = (unsigned)(2 * tb + 2);

            if (pf) {
                #pragma unroll
                for (int s = 0; s < 2; ++s) {
                    nidS[s] = nidN[s]; tsS[s] = tsN[s]; e0S[s] = e0N[s];
                    if (is_src) {
                        nskS[s] = __shfl(ra[s].x, i16);
                        nf0S[s] = make_uint4(pk2u(ra[s].x,ra[s].y), pk2u(ra[s].z,ra[s].w),
                                             pk2u(rb[s].x,rb[s].y), pk2u(rb[s].z,rb[s].w));
                        nf1S[s] = make_uint4(pk2u(rc[s].x,rc[s].y), pk2u(rc[s].z,rc[s].w),
                                             pk2u(rd[s].x,rd[s].y), pk2u(rd[s].z,rd[s].w));
                    }
                }
            }
        }
    } else {
        // ================= CONSUMER =================
        uint4 whh[12][2];
        #pragma unroll
        for (int mt = 0; mt < 12; ++mt)
            #pragma unroll
            for (int kh = 0; kh < 2; ++kh)
                whh[mt][kh] = pkf8(WH + (size_t)(16 * mt + i16) * 64 + 32 * kh + 8 * g);
        floatx4 bhn[4];
        #pragma unroll
        for (int mt = 0; mt < 4; ++mt) {
            floatx4 v;
            #pragma unroll
            for (int r = 0; r < 4; ++r) v[r] = BH[128 + 16 * mt + 4 * g + r];
            bhn[mt] = v;
        }
        _Float16* hb = hbuf[chain];
        for (int q = lane; q < 576; q += 64) ((uint32_t*)hb)[q] = 0u;

        floatx4 hM[4] = {{0,0,0,0},{0,0,0,0},{0,0,0,0},{0,0,0,0}};

        for (int t = 0; t < NN; ++t) {
            while (vp[chain] < (unsigned)(t + 1)) __builtin_amdgcn_s_sleep(1);
            __threadfence_block();
            const int sl = t & 1;
            uint4 u0 = ring[chain][sl][0][lane], u1 = ring[chain][sl][1][lane];
            uint4 u2 = ring[chain][sl][2][lane], u3 = ring[chain][sl][3][lane];
            uint4 u4 = ring[chain][sl][4][lane], u5 = ring[chain][sl][5][lane];
            floatx4 gi[12];
            gi[0]  = up4(make_uint2(u0.x, u0.y)); gi[1]  = up4(make_uint2(u0.z, u0.w));
            gi[2]  = up4(make_uint2(u1.x, u1.y)); gi[3]  = up4(make_uint2(u1.z, u1.w));
            gi[4]  = up4(make_uint2(u2.x, u2.y)); gi[5]  = up4(make_uint2(u2.z, u2.w));
            gi[6]  = up4(make_uint2(u3.x, u3.y)); gi[7]  = up4(make_uint2(u3.z, u3.w));
            gi[8]  = up4(make_uint2(u4.x, u4.y)); gi[9]  = up4(make_uint2(u4.z, u4.w));
            gi[10] = up4(make_uint2(u5.x, u5.y)); gi[11] = up4(make_uint2(u5.z, u5.w));
            __threadfence_block();
            if (lane == 0) vc[chain] = (unsigned)(t + 1);

            half8 hB0 = u2h(*(const uint4*)&hb[i16 * 72 + 8 * g]);
            half8 hB1 = u2h(*(const uint4*)&hb[i16 * 72 + 32 + 8 * g]);
            floatx4 ga[12];
            #pragma unroll
            for (int mt = 0; mt < 8; ++mt) {
                floatx4 c = MFMA(u2h(whh[mt][0]), hB0, gi[mt]);
                ga[mt] = MFMA(u2h(whh[mt][1]), hB1, c);
            }
            #pragma unroll
            for (int mt = 8; mt < 12; ++mt) {
                floatx4 c = MFMA(u2h(whh[mt][0]), hB0, bhn[mt - 8]);
                ga[mt] = MFMA(u2h(whh[mt][1]), hB1, c);
            }
            // gates via table lerp (sigma(x) = 0.5 + 0.5*tanh(x/2))
            #pragma unroll
            for (int mt = 0; mt < 4; ++mt) {
                #pragma unroll
                for (int r = 0; r < 4; ++r) {
                    float rr = fmaf(tlerp(ttab, fmaf(ga[mt][r],     64.0f, 1024.0f)), 0.5f, 0.5f);
                    float zz = fmaf(tlerp(ttab, fmaf(ga[4 + mt][r], 64.0f, 1024.0f)), 0.5f, 0.5f);
                    float nn = tlerp(ttab, fmaf(fmaf(rr, ga[8 + mt][r], gi[8 + mt][r]), 128.0f, 1024.0f));
                    hM[mt][r] = nn + zz * (hM[mt][r] - nn);
                }
            }
            #pragma unroll
            for (int mt = 0; mt < 4; ++mt)
                *(uint2*)&hb[i16 * 72 + 16 * mt + 4 * g] = pkx4(hM[mt]);
        }

        // ---- tail ----
        float twc[8], tbc[8];
        #pragma unroll
        for (int j = 0; j < 8; ++j) {
            twc[j] = time_w[8 * (g & 1) + j];
            tbc[j] = time_b[8 * (g & 1) + j];
        }
        const int didL = dst_ids[b];
        float e00 = edgef[0];
        uint4 wtTr[4];
        #pragma unroll
        for (int mt = 0; mt < 4; ++mt) {
            float v[8];
            #pragma unroll
            for (int j = 0; j < 8; ++j) {
                int k = 8 * g + j, dim = 16 * mt + i16;
                float x = 0.0f;
                if (k < 16)       x = W_time[k * 64 + dim];
                else if (k == 16) x = W_edge[dim];
                else if (k == 17) x = W_str[dim];
                else if (k == 18) x = b_edge[dim] + b_time[dim];
                else if (k == 20) x = b_feat[dim];
                v[j] = x;
            }
            wtTr[mt] = make_uint4(pk2u(v[0],v[1]), pk2u(v[2],v[3]), pk2u(v[4],v[5]), pk2u(v[6],v[7]));
        }
        uint4 tt4;
        if (g < 2) {
            float cv[8];
            #pragma unroll
            for (int j = 0; j < 8; ++j) cv[j] = __cosf(tbc[j]);
            tt4 = make_uint4(pk2u(cv[0],cv[1]), pk2u(cv[2],cv[3]), pk2u(cv[4],cv[5]), pk2u(cv[6],cv[7]));
        } else if (g == 2) {
            tt4 = make_uint4(pk2u(e00, 0.0f), pk2u(1.0f, 0.0f), pk2u(is_src ? 0.0f : 1.0f, 0.0f), 0u);
        } else {
            tt4 = make_uint4(0u, 0u, 0u, 0u);
        }
        half8 tT = u2h(tt4);

        floatx4 tacc[4];
        #pragma unroll
        for (int mt = 0; mt < 4; ++mt) tacc[mt] = MFMA(u2h(wtTr[mt]), tT, z4);
        if (!is_src) {
            const float* rp = nodef + (size_t)didL * 64 + 8 * g;
            float4 a = *(const float4*)rp,        c = *(const float4*)(rp + 4);
            float4 d = *(const float4*)(rp + 32), e = *(const float4*)(rp + 36);
            uint4 d0 = make_uint4(pk2u(a.x,a.y), pk2u(a.z,a.w), pk2u(c.x,c.y), pk2u(c.z,c.w));
            uint4 d1 = make_uint4(pk2u(d.x,d.y), pk2u(d.z,d.w), pk2u(e.x,e.y), pk2u(e.z,e.w));
            #pragma unroll
            for (int mt = 0; mt < 4; ++mt) {
                uint4 G0 = *(const uint4*)&Gsh[(16 * mt + i16) * 72 + 8 * g];
                uint4 G1 = *(const uint4*)&Gsh[(16 * mt + i16) * 72 + 32 + 8 * g];
                tacc[mt] = MFMA(u2h(G0), u2h(d0), tacc[mt]);
                tacc[mt] = MFMA(u2h(G1), u2h(d1), tacc[mt]);
            }
        }

        // W_out^T A-frags -> registers (tail only; whh dead by now)
        uint4 woR[8];
        #pragma unroll
        for (int tt = 0; tt < 8; ++tt) {
            int kh = tt >> 2, mt = tt & 3;
            float w[8];
            #pragma unroll
            for (int j = 0; j < 8; ++j)
                w[j] = W_out[(32 * kh + 8 * g + j) * 64 + 16 * mt + i16];
            woR[tt] = make_uint4(pk2u(w[0],w[1]), pk2u(w[2],w[3]), pk2u(w[4],w[5]), pk2u(w[6],w[7]));
        }

        #pragma unroll
        for (int mt = 0; mt < 4; ++mt) {
            floatx4 e4 = hM[mt] + tacc[mt];
            *(uint2*)&hb[i16 * 72 + 16 * mt + 4 * g] = pkx4(e4);
        }
        half8 eB0 = u2h(*(const uint4*)&hb[i16 * 72 + 8 * g]);
        half8 eB1 = u2h(*(const uint4*)&hb[i16 * 72 + 32 + 8 * g]);

        const size_t obase = (is_src ? 0 : (size_t)BB * 64) + (size_t)(ib0 + i16) * 64;
        #pragma unroll
        for (int mt = 0; mt < 4; ++mt) {
            floatx4 bo;
            #pragma unroll
            for (int r = 0; r < 4; ++r) bo[r] = b_out[16 * mt + 4 * g + r];
            floatx4 o = MFMA(u2h(woR[mt]), eB0, bo);
            o = MFMA(u2h(woR[4 + mt]), eB1, o);
            #pragma unroll
            for (int r = 0; r < 4; ++r)
                out[obase + 16 * mt + 4 * g + r] = o[r];
        }
    }
}

extern "C" void kernel_launch(void* const* d_in, const int* in_sizes, int n_in,
                              void* d_out, int out_size, void* d_ws, size_t ws_size,
                              hipStream_t stream) {
    (void)in_sizes; (void)n_in; (void)d_ws; (void)ws_size; (void)out_size;
    const float* nodef  = (const float*)d_in[0];
    const float* edgef  = (const float*)d_in[1];
    const int*   srcid  = (const int*)  d_in[2];
    const int*   dstid  = (const int*)  d_in[3];
    const float* times  = (const float*)d_in[4];
    const int*   s_nids = (const int*)  d_in[5];
    const int*   s_eids = (const int*)  d_in[6];
    const float* s_ts   = (const float*)d_in[7];
    const int*   d_nids = (const int*)  d_in[8];
    const int*   d_eids = (const int*)  d_in[9];
    const float* d_ts   = (const float*)d_in[10];
    const float* W_feat = (const float*)d_in[11];
    const float* b_feat = (const float*)d_in[12];
    const float* W_edge = (const float*)d_in[13];
    const float* b_edge = (const float*)d_in[14];
    const float* W_time = (const float*)d_in[15];
    const float* b_time = (const float*)d_in[16];
    const float* W_str  = (const float*)d_in[17];
    const float* b_str  = (const float*)d_in[18];
    const float* W_out  = (const float*)d_in[19];
    const float* b_out  = (const float*)d_in[20];
    const float* time_w = (const float*)d_in[21];
    const float* time_b = (const float*)d_in[22];
    const float* sWih   = (const float*)d_in[23];
    const float* sWhh   = (const float*)d_in[24];
    const float* sbih   = (const float*)d_in[25];
    const float* sbhh   = (const float*)d_in[26];
    const float* dWih   = (const float*)d_in[27];
    const float* dWhh   = (const float*)d_in[28];
    const float* dbih   = (const float*)d_in[29];
    const float* dbhh   = (const float*)d_in[30];

    dim3 grid(512), block(256);
    dygkt6<<<grid, block, 0, stream>>>(
        nodef, edgef, srcid, dstid, times,
        s_nids, s_eids, s_ts, d_nids, d_eids, d_ts,
        W_feat, b_feat, W_edge, b_edge, W_time, b_time,
        W_str, b_str, W_out, b_out, time_w, time_b,
        sWih, sWhh, sbih, sbhh, dWih, dWhh, dbih, dbhh,
        (float*)d_out);
}